// Round 2
// baseline (696.371 us; speedup 1.0000x reference)
//
#include <hip/hip_runtime.h>
#include <stdint.h>

// SageLayer: N=8192, F=1024, O=1024, K=2F=2048, NUM_NEIGH=10
#define NN 8192
#define FD 1024
#define OD 1024
#define KD 2048
#define NB 10

typedef short bf16x8 __attribute__((ext_vector_type(8)));
typedef float f32x4  __attribute__((ext_vector_type(4)));

static __device__ __forceinline__ float bf2f(ushort u) {
  union { uint32_t i; float f; } v; v.i = ((uint32_t)u) << 16; return v.f;
}
static __device__ __forceinline__ ushort f2bf(float f) {
  union { float f; uint32_t i; } v; v.f = f;
  uint32_t x = v.i;
  return (ushort)((x + 0x7FFFu + ((x >> 16) & 1u)) >> 16);  // RNE
}

// ---------------------------------------------------------------------------
// Dtype sniffer: X ~ N(0,1). If stored bf16, every ushort has exponent field
// <= ~0x81 (|v| < 8). If stored f32, the LOW half-ushort of each float is
// uniform mantissa junk -> exponent field > 0x83 with ~50% probability.
// flag = 1 -> bf16 data, flag = 0 -> f32 data.
// ---------------------------------------------------------------------------
__global__ void sniff_kernel(const ushort* __restrict__ X, int* __restrict__ flag) {
  int c = 0;
  for (int i = threadIdx.x; i < 256; i += 64) {
    const int e = (X[i] >> 7) & 0xFF;
    if (e > 0x83) c = 1;  // |decoded bf16| > 16: impossible for true bf16 N(0,1)
  }
  unsigned long long any = __ballot(c != 0);
  if (threadIdx.x == 0) flag[0] = (any == 0ULL) ? 1 : 0;
}

// load 8 consecutive elements starting at elem index e, as bf16x8
static __device__ __forceinline__ bf16x8 load8cvt(const void* base, size_t e, bool isf32) {
  if (!isf32) {
    return *reinterpret_cast<const bf16x8*>((const ushort*)base + e);
  }
  const float* p = (const float*)base + e;
  const float4 a = *(const float4*)p;
  const float4 b = *(const float4*)(p + 4);
  bf16x8 r;
  r[0] = (short)f2bf(a.x); r[1] = (short)f2bf(a.y);
  r[2] = (short)f2bf(a.z); r[3] = (short)f2bf(a.w);
  r[4] = (short)f2bf(b.x); r[5] = (short)f2bf(b.y);
  r[6] = (short)f2bf(b.z); r[7] = (short)f2bf(b.w);
  return r;
}

// accumulate 8 consecutive elements into o[8] (f32)
static __device__ __forceinline__ void load8acc(const void* base, size_t e, bool isf32,
                                                float* o) {
  if (isf32) {
    const float* p = (const float*)base + e;
    const float4 a = *(const float4*)p;
    const float4 b = *(const float4*)(p + 4);
    o[0] += a.x; o[1] += a.y; o[2] += a.z; o[3] += a.w;
    o[4] += b.x; o[5] += b.y; o[6] += b.z; o[7] += b.w;
  } else {
    const uint4 v = *(const uint4*)((const ushort*)base + e);
    const ushort* u = (const ushort*)&v;
#pragma unroll
    for (int i = 0; i < 8; ++i) o[i] += bf2f(u[i]);
  }
}

// ---------------------------------------------------------------------------
// Fused GEMM: out = [X | mean(X[idx])] @ W + b.
// 128x128 tile, BK=32, 4 waves x (4x4) mfma_16x16x32_bf16. ZERO workspace
// (beyond the 4-byte dtype flag): agg tiles are computed on the fly into LDS;
// W staged [k][n]-packed, B-fragments read as 8 scalar LDS reads.
// ---------------------------------------------------------------------------
__global__ __launch_bounds__(256) void gemm_kernel(const void* __restrict__ X,
                                                   const void* __restrict__ W,
                                                   const void* __restrict__ Bias,
                                                   const int* __restrict__ idx,
                                                   const int* __restrict__ flag,
                                                   void* __restrict__ Out) {
  const bool isf32 = (flag[0] == 0);
  __shared__ ushort lA[128 * 32];  // [m][k] packed, 8 KB
  __shared__ ushort lB[32 * 128];  // [k][n] packed, 8 KB
  const int t    = threadIdx.x;
  const int m0   = blockIdx.y * 128;
  const int n0   = blockIdx.x * 128;
  const int wave = t >> 6;
  const int lane = t & 63;
  const int wm   = (wave & 1) * 64;
  const int wn   = (wave >> 1) * 64;
  const int l15  = lane & 15;
  const int quad = lane >> 4;

  f32x4 acc[4][4];
#pragma unroll
  for (int i = 0; i < 4; ++i)
#pragma unroll
    for (int j = 0; j < 4; ++j) acc[i][j] = (f32x4){0.f, 0.f, 0.f, 0.f};

  for (int kt = 0; kt < KD / 32; ++kt) {
    const int k0 = kt * 32;

    // ---- stage A tile 128x32 ----
    if (k0 < FD) {
#pragma unroll
      for (int r = 0; r < 2; ++r) {
        const int q = r * 256 + t;           // 0..511
        const int row = q >> 2, ch = q & 3;  // row 0..127, 8-elem chunk 0..3
        const bf16x8 v = load8cvt(X, (size_t)(m0 + row) * FD + k0 + ch * 8, isf32);
        *reinterpret_cast<bf16x8*>(lA + q * 8) = v;
      }
    } else {
      const int kc = k0 - FD;  // column offset into X for the agg half
#pragma unroll
      for (int r = 0; r < 2; ++r) {
        const int q = r * 256 + t;
        const int row = q >> 2, ch = q & 3;
        float a8[8] = {0.f, 0.f, 0.f, 0.f, 0.f, 0.f, 0.f, 0.f};
        const int* ip = idx + (size_t)(m0 + row) * NB;
#pragma unroll
        for (int j = 0; j < NB; ++j)
          load8acc(X, (size_t)ip[j] * FD + kc + ch * 8, isf32, a8);
        bf16x8 v;
#pragma unroll
        for (int e = 0; e < 8; ++e) v[e] = (short)f2bf(a8[e] * 0.1f);
        *reinterpret_cast<bf16x8*>(lA + q * 8) = v;
      }
    }

    // ---- stage B tile 32x128 ([k][n] packed) ----
#pragma unroll
    for (int r = 0; r < 2; ++r) {
      const int q = r * 256 + t;
      const int kr = q >> 4, ch = q & 15;  // k-row 0..31, n-chunk 0..15
      const bf16x8 v = load8cvt(W, (size_t)(k0 + kr) * OD + n0 + ch * 8, isf32);
      *reinterpret_cast<bf16x8*>(lB + q * 8) = v;
    }
    __syncthreads();

    // ---- fragments ----
    bf16x8 afr[4], bfr[4];
#pragma unroll
    for (int mi = 0; mi < 4; ++mi)
      afr[mi] = *reinterpret_cast<const bf16x8*>(lA + (wm + mi * 16 + l15) * 32 + quad * 8);
#pragma unroll
    for (int ni = 0; ni < 4; ++ni) {
      const int col = wn + ni * 16 + l15;
#pragma unroll
      for (int j = 0; j < 8; ++j)
        bfr[ni][j] = (short)lB[(quad * 8 + j) * 128 + col];
    }
#pragma unroll
    for (int mi = 0; mi < 4; ++mi)
#pragma unroll
      for (int ni = 0; ni < 4; ++ni)
        acc[mi][ni] = __builtin_amdgcn_mfma_f32_16x16x32_bf16(afr[mi], bfr[ni], acc[mi][ni], 0, 0, 0);
    __syncthreads();
  }

  // ---- epilogue: C/D layout col=lane&15, row=quad*4+reg ----
#pragma unroll
  for (int ni = 0; ni < 4; ++ni) {
    const int gn = n0 + wn + ni * 16 + l15;
    const float bv = isf32 ? ((const float*)Bias)[gn] : bf2f(((const ushort*)Bias)[gn]);
#pragma unroll
    for (int mi = 0; mi < 4; ++mi) {
      const int gm = m0 + wm + mi * 16 + quad * 4;
#pragma unroll
      for (int r = 0; r < 4; ++r) {
        const float v = acc[mi][ni][r] + bv;
        const size_t pos = (size_t)(gm + r) * OD + gn;
        if (isf32) ((float*)Out)[pos] = v;
        else       ((ushort*)Out)[pos] = f2bf(v);
      }
    }
  }
}

extern "C" void kernel_launch(void* const* d_in, const int* in_sizes, int n_in,
                              void* d_out, int out_size, void* d_ws, size_t ws_size,
                              hipStream_t stream) {
  const void* X   = d_in[0];
  // d_in[1] = A: dead code in the reference
  const void* W   = d_in[2];
  const void* b   = d_in[3];
  const int*  idx = (const int*)d_in[4];

  int* flag = (int*)d_ws;  // 4 bytes only

  sniff_kernel<<<1, 64, 0, stream>>>((const ushort*)X, flag);

  dim3 gg(OD / 128, NN / 128);
  gemm_kernel<<<gg, 256, 0, stream>>>(X, W, b, idx, flag, d_out);
}

// Round 3
// 423.842 us; speedup vs baseline: 1.6430x; 1.6430x over previous
//
#include <hip/hip_runtime.h>
#include <stdint.h>

// SageLayer: N=8192, F=1024, O=1024, K=2F=2048, NUM_NEIGH=10. Inputs f32.
#define NN 8192
#define FD 1024
#define OD 1024
#define KD 2048
#define NB 10

typedef short bf16x8 __attribute__((ext_vector_type(8)));
typedef float f32x4  __attribute__((ext_vector_type(4)));

static __device__ __forceinline__ ushort f2bf(float f) {
  union { float f; uint32_t i; } v; v.f = f;
  uint32_t x = v.i;
  return (ushort)((x + 0x7FFFu + ((x >> 16) & 1u)) >> 16);  // RNE
}

// async global->LDS, 16 B/lane. LDS dest must be wave-uniform base + lane*16.
static __device__ __forceinline__ void async16(const ushort* g, ushort* l) {
  __builtin_amdgcn_global_load_lds(
      (const __attribute__((address_space(1))) uint32_t*)(const void*)g,
      (__attribute__((address_space(3))) uint32_t*)(void*)l, 16, 0, 0);
}

// ---------------------------------------------------------------------------
// agg_f32: aggb[n][f] = bf16(mean_j X[idx[n][j]][f]). One row per 256-thread
// block; each thread owns one float4 column group; 10 independent gathers.
// ---------------------------------------------------------------------------
__global__ __launch_bounds__(256) void agg_f32(const float* __restrict__ X,
                                               const int* __restrict__ idx,
                                               ushort* __restrict__ aggb) {
  const int row = blockIdx.x;
  const int c4  = threadIdx.x;  // 0..255 -> cols c4*4..c4*4+3
  const int* ip = idx + (size_t)row * NB;
  int nb[NB];
#pragma unroll
  for (int j = 0; j < NB; ++j) nb[j] = ip[j];
  float4 acc = make_float4(0.f, 0.f, 0.f, 0.f);
#pragma unroll
  for (int j = 0; j < NB; ++j) {
    const float4 v = *reinterpret_cast<const float4*>(X + (size_t)nb[j] * FD + c4 * 4);
    acc.x += v.x; acc.y += v.y; acc.z += v.z; acc.w += v.w;
  }
  ushort o[4];
  o[0] = f2bf(acc.x * 0.1f); o[1] = f2bf(acc.y * 0.1f);
  o[2] = f2bf(acc.z * 0.1f); o[3] = f2bf(acc.w * 0.1f);
  *reinterpret_cast<uint2*>(aggb + (size_t)row * FD + c4 * 4) =
      *reinterpret_cast<const uint2*>(o);
}

// ---------------------------------------------------------------------------
// wconv: Wtb[n][k] = bf16(W[k][n]).  64x64 LDS-tiled transpose + convert.
// ---------------------------------------------------------------------------
__global__ __launch_bounds__(1024) void wconv(const float* __restrict__ W,
                                              ushort* __restrict__ Wtb) {
  __shared__ float tile[64][65];
  const int k0 = blockIdx.x * 64;
  const int n0 = blockIdx.y * 64;
  const int tx = threadIdx.x;  // 0..63
  const int ty = threadIdx.y;  // 0..15
#pragma unroll
  for (int r = 0; r < 4; ++r) {
    const int kl = ty + r * 16;
    tile[kl][tx] = W[(size_t)(k0 + kl) * OD + n0 + tx];
  }
  __syncthreads();
#pragma unroll
  for (int r = 0; r < 4; ++r) {
    const int nl = ty + r * 16;
    Wtb[(size_t)(n0 + nl) * KD + k0 + tx] = f2bf(tile[tx][nl]);
  }
}

// ---------------------------------------------------------------------------
// gemm_fast: out = [X | aggb] @ W + b  via Wtb (B^T, [n][k] bf16).
// 128x128 tile, BK=32, 4 waves x (4x4) mfma_16x16x32_bf16 (m97 structure).
// A left half: float4 load + convert + ds_write_b128. A right half + B:
// global_load_lds width 16. Fragments: ds_read_b128, K-contiguous.
// ---------------------------------------------------------------------------
__global__ __launch_bounds__(256, 2) void gemm_fast(const float* __restrict__ X,
                                                    const ushort* __restrict__ aggb,
                                                    const ushort* __restrict__ Wtb,
                                                    const float* __restrict__ Bias,
                                                    float* __restrict__ Out) {
  __shared__ ushort lA[128 * 32];  // [m][k] packed, 8 KB
  __shared__ ushort lB[128 * 32];  // [n][k] packed, 8 KB
  const int t    = threadIdx.x;
  const int m0   = blockIdx.y * 128;
  const int n0   = blockIdx.x * 128;
  const int wave = t >> 6;
  const int lane = t & 63;
  const int wm   = (wave & 1) * 64;
  const int wn   = (wave >> 1) * 64;
  const int l15  = lane & 15;
  const int quad = lane >> 4;

  f32x4 acc[4][4];
#pragma unroll
  for (int i = 0; i < 4; ++i)
#pragma unroll
    for (int j = 0; j < 4; ++j) acc[i][j] = (f32x4){0.f, 0.f, 0.f, 0.f};

  for (int kt = 0; kt < KD / 32; ++kt) {
    const int k0 = kt * 32;
    // ---- B tile 128x32 ([n][k] packed): async16 ----
#pragma unroll
    for (int r = 0; r < 2; ++r) {
      const int q = r * 256 + t;           // 0..511
      const int row = q >> 2, ch = q & 3;  // n-local row, 8-elem chunk
      async16(Wtb + (size_t)(n0 + row) * KD + k0 + ch * 8, lB + q * 8);
    }
    // ---- A tile 128x32 ----
    if (k0 < FD) {
      // left half: X (f32) -> convert -> LDS
#pragma unroll
      for (int r = 0; r < 2; ++r) {
        const int q = r * 256 + t;
        const int row = q >> 2, ch = q & 3;
        const float* p = X + (size_t)(m0 + row) * FD + k0 + ch * 8;
        const float4 a = *reinterpret_cast<const float4*>(p);
        const float4 b = *reinterpret_cast<const float4*>(p + 4);
        bf16x8 v;
        v[0] = (short)f2bf(a.x); v[1] = (short)f2bf(a.y);
        v[2] = (short)f2bf(a.z); v[3] = (short)f2bf(a.w);
        v[4] = (short)f2bf(b.x); v[5] = (short)f2bf(b.y);
        v[6] = (short)f2bf(b.z); v[7] = (short)f2bf(b.w);
        *reinterpret_cast<bf16x8*>(lA + q * 8) = v;
      }
    } else {
      // right half: precomputed aggb (bf16) via async16
      const int kc = k0 - FD;
#pragma unroll
      for (int r = 0; r < 2; ++r) {
        const int q = r * 256 + t;
        const int row = q >> 2, ch = q & 3;
        async16(aggb + (size_t)(m0 + row) * FD + kc + ch * 8, lA + q * 8);
      }
    }
    __syncthreads();  // drains vmcnt (async) + lgkmcnt (ds_write)

    bf16x8 afr[4], bfr[4];
#pragma unroll
    for (int mi = 0; mi < 4; ++mi)
      afr[mi] = *reinterpret_cast<const bf16x8*>(lA + (wm + mi * 16 + l15) * 32 + quad * 8);
#pragma unroll
    for (int ni = 0; ni < 4; ++ni)
      bfr[ni] = *reinterpret_cast<const bf16x8*>(lB + (wn + ni * 16 + l15) * 32 + quad * 8);
#pragma unroll
    for (int mi = 0; mi < 4; ++mi)
#pragma unroll
      for (int ni = 0; ni < 4; ++ni)
        acc[mi][ni] = __builtin_amdgcn_mfma_f32_16x16x32_bf16(afr[mi], bfr[ni], acc[mi][ni], 0, 0, 0);
    __syncthreads();
  }

  // ---- epilogue: C/D layout col=lane&15, row=quad*4+reg (verified r2) ----
#pragma unroll
  for (int ni = 0; ni < 4; ++ni) {
    const int gn = n0 + wn + ni * 16 + l15;
    const float bv = Bias[gn];
#pragma unroll
    for (int mi = 0; mi < 4; ++mi) {
      const int gm = m0 + wm + mi * 16 + quad * 4;
#pragma unroll
      for (int r = 0; r < 4; ++r)
        Out[(size_t)(gm + r) * OD + gn] = acc[mi][ni][r] + bv;
    }
  }
}

// ---------------------------------------------------------------------------
// Fallback (ws too small): round-2 fused kernel, f32-only. Known-correct.
// ---------------------------------------------------------------------------
__global__ __launch_bounds__(256) void gemm_fused(const float* __restrict__ X,
                                                  const float* __restrict__ W,
                                                  const float* __restrict__ Bias,
                                                  const int* __restrict__ idx,
                                                  float* __restrict__ Out) {
  __shared__ ushort lA[128 * 32];
  __shared__ ushort lB[32 * 128];
  const int t    = threadIdx.x;
  const int m0   = blockIdx.y * 128;
  const int n0   = blockIdx.x * 128;
  const int wave = t >> 6;
  const int lane = t & 63;
  const int wm   = (wave & 1) * 64;
  const int wn   = (wave >> 1) * 64;
  const int l15  = lane & 15;
  const int quad = lane >> 4;

  f32x4 acc[4][4];
#pragma unroll
  for (int i = 0; i < 4; ++i)
#pragma unroll
    for (int j = 0; j < 4; ++j) acc[i][j] = (f32x4){0.f, 0.f, 0.f, 0.f};

  for (int kt = 0; kt < KD / 32; ++kt) {
    const int k0 = kt * 32;
    if (k0 < FD) {
#pragma unroll
      for (int r = 0; r < 2; ++r) {
        const int q = r * 256 + t;
        const int row = q >> 2, ch = q & 3;
        const float* p = X + (size_t)(m0 + row) * FD + k0 + ch * 8;
        const float4 a = *(const float4*)p;
        const float4 b = *(const float4*)(p + 4);
        bf16x8 v;
        v[0] = (short)f2bf(a.x); v[1] = (short)f2bf(a.y);
        v[2] = (short)f2bf(a.z); v[3] = (short)f2bf(a.w);
        v[4] = (short)f2bf(b.x); v[5] = (short)f2bf(b.y);
        v[6] = (short)f2bf(b.z); v[7] = (short)f2bf(b.w);
        *reinterpret_cast<bf16x8*>(lA + q * 8) = v;
      }
    } else {
      const int kc = k0 - FD;
#pragma unroll
      for (int r = 0; r < 2; ++r) {
        const int q = r * 256 + t;
        const int row = q >> 2, ch = q & 3;
        float a8[8] = {0.f, 0.f, 0.f, 0.f, 0.f, 0.f, 0.f, 0.f};
        const int* ip = idx + (size_t)(m0 + row) * NB;
#pragma unroll
        for (int j = 0; j < NB; ++j) {
          const float* p = X + (size_t)ip[j] * FD + kc + ch * 8;
          const float4 a = *(const float4*)p;
          const float4 b = *(const float4*)(p + 4);
          a8[0] += a.x; a8[1] += a.y; a8[2] += a.z; a8[3] += a.w;
          a8[4] += b.x; a8[5] += b.y; a8[6] += b.z; a8[7] += b.w;
        }
        bf16x8 v;
#pragma unroll
        for (int e = 0; e < 8; ++e) v[e] = (short)f2bf(a8[e] * 0.1f);
        *reinterpret_cast<bf16x8*>(lA + q * 8) = v;
      }
    }
#pragma unroll
    for (int r = 0; r < 2; ++r) {
      const int q = r * 256 + t;
      const int kr = q >> 4, ch = q & 15;
      const float* p = W + (size_t)(k0 + kr) * OD + n0 + ch * 8;
      const float4 a = *(const float4*)p;
      const float4 b = *(const float4*)(p + 4);
      bf16x8 v;
      v[0] = (short)f2bf(a.x); v[1] = (short)f2bf(a.y);
      v[2] = (short)f2bf(a.z); v[3] = (short)f2bf(a.w);
      v[4] = (short)f2bf(b.x); v[5] = (short)f2bf(b.y);
      v[6] = (short)f2bf(b.z); v[7] = (short)f2bf(b.w);
      *reinterpret_cast<bf16x8*>(lB + q * 8) = v;
    }
    __syncthreads();

    bf16x8 afr[4], bfr[4];
#pragma unroll
    for (int mi = 0; mi < 4; ++mi)
      afr[mi] = *reinterpret_cast<const bf16x8*>(lA + (wm + mi * 16 + l15) * 32 + quad * 8);
#pragma unroll
    for (int ni = 0; ni < 4; ++ni) {
      const int col = wn + ni * 16 + l15;
#pragma unroll
      for (int j = 0; j < 8; ++j)
        bfr[ni][j] = (short)lB[(quad * 8 + j) * 128 + col];
    }
#pragma unroll
    for (int mi = 0; mi < 4; ++mi)
#pragma unroll
      for (int ni = 0; ni < 4; ++ni)
        acc[mi][ni] = __builtin_amdgcn_mfma_f32_16x16x32_bf16(afr[mi], bfr[ni], acc[mi][ni], 0, 0, 0);
    __syncthreads();
  }
#pragma unroll
  for (int ni = 0; ni < 4; ++ni) {
    const int gn = n0 + wn + ni * 16 + l15;
    const float bv = Bias[gn];
#pragma unroll
    for (int mi = 0; mi < 4; ++mi) {
      const int gm = m0 + wm + mi * 16 + quad * 4;
#pragma unroll
      for (int r = 0; r < 4; ++r)
        Out[(size_t)(gm + r) * OD + gn] = acc[mi][ni][r] + bv;
    }
  }
}

extern "C" void kernel_launch(void* const* d_in, const int* in_sizes, int n_in,
                              void* d_out, int out_size, void* d_ws, size_t ws_size,
                              hipStream_t stream) {
  const float* X   = (const float*)d_in[0];
  // d_in[1] = A: dead code in the reference
  const float* W   = (const float*)d_in[2];
  const float* b   = (const float*)d_in[3];
  const int*   idx = (const int*)d_in[4];
  float* out = (float*)d_out;

  const size_t need = ((size_t)NN * FD + (size_t)OD * KD) * sizeof(ushort);  // 20 MB
  if (ws_size >= need) {
    ushort* aggb = (ushort*)d_ws;                 // [8192][1024] bf16, 16 MB
    ushort* Wtb  = aggb + (size_t)NN * FD;        // [1024][2048] bf16, 4 MB

    agg_f32<<<NN, 256, 0, stream>>>(X, idx, aggb);
    wconv<<<dim3(KD / 64, OD / 64), dim3(64, 16), 0, stream>>>(W, Wtb);
    gemm_fast<<<dim3(OD / 128, NN / 128), 256, 0, stream>>>(X, aggb, Wtb, b, out);
  } else {
    gemm_fused<<<dim3(OD / 128, NN / 128), 256, 0, stream>>>(X, W, b, idx, out);
  }
}

// Round 4
// 402.432 us; speedup vs baseline: 1.7304x; 1.0532x over previous
//
#include <hip/hip_runtime.h>
#include <stdint.h>

// SageLayer: N=8192, F=1024, O=1024, K=2F=2048, NUM_NEIGH=10. Inputs f32.
#define NN 8192
#define FD 1024
#define OD 1024
#define KD 2048
#define NB 10

typedef short bf16x8 __attribute__((ext_vector_type(8)));
typedef float f32x4  __attribute__((ext_vector_type(4)));

static __device__ __forceinline__ float bf2f(ushort u) {
  union { uint32_t i; float f; } v; v.i = ((uint32_t)u) << 16; return v.f;
}
static __device__ __forceinline__ ushort f2bf(float f) {
  union { float f; uint32_t i; } v; v.f = f;
  uint32_t x = v.i;
  return (ushort)((x + 0x7FFFu + ((x >> 16) & 1u)) >> 16);  // RNE
}
static __device__ __forceinline__ bf16x8 cvt8(const float* p) {
  const float4 a = *reinterpret_cast<const float4*>(p);
  const float4 b = *reinterpret_cast<const float4*>(p + 4);
  bf16x8 v;
  v[0] = (short)f2bf(a.x); v[1] = (short)f2bf(a.y);
  v[2] = (short)f2bf(a.z); v[3] = (short)f2bf(a.w);
  v[4] = (short)f2bf(b.x); v[5] = (short)f2bf(b.y);
  v[6] = (short)f2bf(b.z); v[7] = (short)f2bf(b.w);
  return v;
}

// async global->LDS, 16 B/lane. LDS dest must be wave-uniform base + lane*16.
static __device__ __forceinline__ void async16(const ushort* g, ushort* l) {
  __builtin_amdgcn_global_load_lds(
      (const __attribute__((address_space(1))) uint32_t*)(const void*)g,
      (__attribute__((address_space(3))) uint32_t*)(void*)l, 16, 0, 0);
}

// ---------------------------------------------------------------------------
// xconv: Ab[i][0:1024] = bf16(X[i][:]).  Ab row stride = KD (2048).
// 128 threads per row-of-1024; 8 elems/thread.
// ---------------------------------------------------------------------------
__global__ __launch_bounds__(256) void xconv(const float* __restrict__ X,
                                             ushort* __restrict__ Ab) {
  const int q   = blockIdx.x * 256 + threadIdx.x;
  const int row = q >> 7;          // 0..8191
  const int col = (q & 127) * 8;   // 0..1016
  const bf16x8 v = cvt8(X + (size_t)row * FD + col);
  *reinterpret_cast<bf16x8*>(Ab + (size_t)row * KD + col) = v;
}

// ---------------------------------------------------------------------------
// aggk: Ab[i][1024:2048] = bf16(mean_j Xb[idx[i][j]][:]), gathering bf16 rows
// from Ab's left half (row stride KD). 2 rows per 256-thread block.
// ---------------------------------------------------------------------------
__global__ __launch_bounds__(256) void aggk(const int* __restrict__ idx,
                                            ushort* __restrict__ Ab) {
  const int row  = blockIdx.x * 2 + (threadIdx.x >> 7);
  const int lane = threadIdx.x & 127;
  const int col  = lane * 8;
  const int* ip = idx + (size_t)row * NB;
  int nb[NB];
#pragma unroll
  for (int j = 0; j < NB; ++j) nb[j] = ip[j];
  float acc[8] = {0.f, 0.f, 0.f, 0.f, 0.f, 0.f, 0.f, 0.f};
#pragma unroll
  for (int j = 0; j < NB; ++j) {
    const uint4 v = *reinterpret_cast<const uint4*>(Ab + (size_t)nb[j] * KD + col);
    const ushort* u = reinterpret_cast<const ushort*>(&v);
#pragma unroll
    for (int e = 0; e < 8; ++e) acc[e] += bf2f(u[e]);
  }
  bf16x8 o;
#pragma unroll
  for (int e = 0; e < 8; ++e) o[e] = (short)f2bf(acc[e] * 0.1f);
  *reinterpret_cast<bf16x8*>(Ab + (size_t)row * KD + FD + col) = o;
}

// ---------------------------------------------------------------------------
// wconv: Wtb[n][k] = bf16(W[k][n]).  64x64 LDS-tiled transpose + convert.
// ---------------------------------------------------------------------------
__global__ __launch_bounds__(1024) void wconv(const float* __restrict__ W,
                                              ushort* __restrict__ Wtb) {
  __shared__ float tile[64][65];
  const int k0 = blockIdx.x * 64;
  const int n0 = blockIdx.y * 64;
  const int tx = threadIdx.x;  // 0..63
  const int ty = threadIdx.y;  // 0..15
#pragma unroll
  for (int r = 0; r < 4; ++r) {
    const int kl = ty + r * 16;
    tile[kl][tx] = W[(size_t)(k0 + kl) * OD + n0 + tx];
  }
  __syncthreads();
#pragma unroll
  for (int r = 0; r < 4; ++r) {
    const int nl = ty + r * 16;
    Wtb[(size_t)(n0 + nl) * KD + k0 + tx] = f2bf(tile[tx][nl]);
  }
}

// ---------------------------------------------------------------------------
// gemm_fast2: Out = Ab @ Wtb^T + b.  Pure m97 structure: 128x128 tile, BK=32,
// 4 waves x (4x4) mfma_16x16x32_bf16, ALL staging via global_load_lds w=16,
// single uniform K-loop (no branch, no convert).
// ---------------------------------------------------------------------------
__global__ __launch_bounds__(256, 2) void gemm_fast2(const ushort* __restrict__ Ab,
                                                     const ushort* __restrict__ Wtb,
                                                     const float* __restrict__ Bias,
                                                     float* __restrict__ Out) {
  __shared__ ushort lA[128 * 32];  // [m][k] packed, 8 KB
  __shared__ ushort lB[128 * 32];  // [n][k] packed, 8 KB
  const int t    = threadIdx.x;
  const int m0   = blockIdx.y * 128;
  const int n0   = blockIdx.x * 128;
  const int wave = t >> 6;
  const int lane = t & 63;
  const int wm   = (wave & 1) * 64;
  const int wn   = (wave >> 1) * 64;
  const int l15  = lane & 15;
  const int quad = lane >> 4;

  f32x4 acc[4][4];
#pragma unroll
  for (int i = 0; i < 4; ++i)
#pragma unroll
    for (int j = 0; j < 4; ++j) acc[i][j] = (f32x4){0.f, 0.f, 0.f, 0.f};

  // per-thread staging coordinates (loop-invariant)
  const int row0 = t >> 2, ch = t & 3;          // round 0: rows 0..63
  const int row1 = (256 + t) >> 2;              // round 1: rows 64..127
  const ushort* gA0 = Ab  + (size_t)(m0 + row0) * KD + ch * 8;
  const ushort* gA1 = Ab  + (size_t)(m0 + row1) * KD + ch * 8;
  const ushort* gB0 = Wtb + (size_t)(n0 + row0) * KD + ch * 8;
  const ushort* gB1 = Wtb + (size_t)(n0 + row1) * KD + ch * 8;

  for (int k0 = 0; k0 < KD; k0 += 32) {
    async16(gA0 + k0, lA + t * 8);
    async16(gA1 + k0, lA + (256 + t) * 8);
    async16(gB0 + k0, lB + t * 8);
    async16(gB1 + k0, lB + (256 + t) * 8);
    __syncthreads();  // drains vmcnt -> staged data visible

    bf16x8 afr[4], bfr[4];
#pragma unroll
    for (int mi = 0; mi < 4; ++mi)
      afr[mi] = *reinterpret_cast<const bf16x8*>(lA + (wm + mi * 16 + l15) * 32 + quad * 8);
#pragma unroll
    for (int ni = 0; ni < 4; ++ni)
      bfr[ni] = *reinterpret_cast<const bf16x8*>(lB + (wn + ni * 16 + l15) * 32 + quad * 8);
#pragma unroll
    for (int mi = 0; mi < 4; ++mi)
#pragma unroll
      for (int ni = 0; ni < 4; ++ni)
        acc[mi][ni] = __builtin_amdgcn_mfma_f32_16x16x32_bf16(afr[mi], bfr[ni], acc[mi][ni], 0, 0, 0);
    __syncthreads();
  }

  // epilogue: C/D layout col=lane&15, row=quad*4+reg (verified r2/r3)
#pragma unroll
  for (int ni = 0; ni < 4; ++ni) {
    const int gn = n0 + wn + ni * 16 + l15;
    const float bv = Bias[gn];
#pragma unroll
    for (int mi = 0; mi < 4; ++mi) {
      const int gm = m0 + wm + mi * 16 + quad * 4;
#pragma unroll
      for (int r = 0; r < 4; ++r)
        Out[(size_t)(gm + r) * OD + gn] = acc[mi][ni][r] + bv;
    }
  }
}

// ---------------------------------------------------------------------------
// Fallback (ws too small): round-2 fused kernel, known-correct.
// ---------------------------------------------------------------------------
__global__ __launch_bounds__(256) void gemm_fused(const float* __restrict__ X,
                                                  const float* __restrict__ W,
                                                  const float* __restrict__ Bias,
                                                  const int* __restrict__ idx,
                                                  float* __restrict__ Out) {
  __shared__ ushort lA[128 * 32];
  __shared__ ushort lB[32 * 128];
  const int t    = threadIdx.x;
  const int m0   = blockIdx.y * 128;
  const int n0   = blockIdx.x * 128;
  const int wave = t >> 6;
  const int lane = t & 63;
  const int wm   = (wave & 1) * 64;
  const int wn   = (wave >> 1) * 64;
  const int l15  = lane & 15;
  const int quad = lane >> 4;

  f32x4 acc[4][4];
#pragma unroll
  for (int i = 0; i < 4; ++i)
#pragma unroll
    for (int j = 0; j < 4; ++j) acc[i][j] = (f32x4){0.f, 0.f, 0.f, 0.f};

  for (int kt = 0; kt < KD / 32; ++kt) {
    const int k0 = kt * 32;
    if (k0 < FD) {
#pragma unroll
      for (int r = 0; r < 2; ++r) {
        const int q = r * 256 + t;
        const int row = q >> 2, ch = q & 3;
        *reinterpret_cast<bf16x8*>(lA + q * 8) =
            cvt8(X + (size_t)(m0 + row) * FD + k0 + ch * 8);
      }
    } else {
      const int kc = k0 - FD;
#pragma unroll
      for (int r = 0; r < 2; ++r) {
        const int q = r * 256 + t;
        const int row = q >> 2, ch = q & 3;
        float a8[8] = {0.f, 0.f, 0.f, 0.f, 0.f, 0.f, 0.f, 0.f};
        const int* ip = idx + (size_t)(m0 + row) * NB;
#pragma unroll
        for (int j = 0; j < NB; ++j) {
          const float* p = X + (size_t)ip[j] * FD + kc + ch * 8;
          const float4 a = *(const float4*)p;
          const float4 b = *(const float4*)(p + 4);
          a8[0] += a.x; a8[1] += a.y; a8[2] += a.z; a8[3] += a.w;
          a8[4] += b.x; a8[5] += b.y; a8[6] += b.z; a8[7] += b.w;
        }
        bf16x8 v;
#pragma unroll
        for (int e = 0; e < 8; ++e) v[e] = (short)f2bf(a8[e] * 0.1f);
        *reinterpret_cast<bf16x8*>(lA + q * 8) = v;
      }
    }
#pragma unroll
    for (int r = 0; r < 2; ++r) {
      const int q = r * 256 + t;
      const int kr = q >> 4, ch = q & 15;
      *reinterpret_cast<bf16x8*>(lB + q * 8) =
          cvt8(W + (size_t)(k0 + kr) * OD + n0 + ch * 8);
    }
    __syncthreads();

    bf16x8 afr[4], bfr[4];
#pragma unroll
    for (int mi = 0; mi < 4; ++mi)
      afr[mi] = *reinterpret_cast<const bf16x8*>(lA + (wm + mi * 16 + l15) * 32 + quad * 8);
#pragma unroll
    for (int ni = 0; ni < 4; ++ni) {
      const int col = wn + ni * 16 + l15;
#pragma unroll
      for (int j = 0; j < 8; ++j)
        bfr[ni][j] = (short)lB[(quad * 8 + j) * 128 + col];
    }
#pragma unroll
    for (int mi = 0; mi < 4; ++mi)
#pragma unroll
      for (int ni = 0; ni < 4; ++ni)
        acc[mi][ni] = __builtin_amdgcn_mfma_f32_16x16x32_bf16(afr[mi], bfr[ni], acc[mi][ni], 0, 0, 0);
    __syncthreads();
  }
#pragma unroll
  for (int ni = 0; ni < 4; ++ni) {
    const int gn = n0 + wn + ni * 16 + l15;
    const float bv = Bias[gn];
#pragma unroll
    for (int mi = 0; mi < 4; ++mi) {
      const int gm = m0 + wm + mi * 16 + quad * 4;
#pragma unroll
      for (int r = 0; r < 4; ++r)
        Out[(size_t)(gm + r) * OD + gn] = acc[mi][ni][r] + bv;
    }
  }
}

extern "C" void kernel_launch(void* const* d_in, const int* in_sizes, int n_in,
                              void* d_out, int out_size, void* d_ws, size_t ws_size,
                              hipStream_t stream) {
  const float* X   = (const float*)d_in[0];
  // d_in[1] = A: dead code in the reference
  const float* W   = (const float*)d_in[2];
  const float* b   = (const float*)d_in[3];
  const int*   idx = (const int*)d_in[4];
  float* out = (float*)d_out;

  const size_t need = ((size_t)NN * KD + (size_t)OD * KD) * sizeof(ushort);  // 36 MB
  if (ws_size >= need) {
    ushort* Ab  = (ushort*)d_ws;                 // [8192][2048] bf16, 32 MB
    ushort* Wtb = Ab + (size_t)NN * KD;          // [1024][2048] bf16, 4 MB

    xconv<<<NN * FD / (256 * 8), 256, 0, stream>>>(X, Ab);
    wconv<<<dim3(KD / 64, OD / 64), dim3(64, 16), 0, stream>>>(W, Wtb);
    aggk<<<NN / 2, 256, 0, stream>>>(idx, Ab);
    gemm_fast2<<<dim3(OD / 128, NN / 128), 256, 0, stream>>>(Ab, Wtb, b, out);
  } else {
    gemm_fused<<<dim3(OD / 128, NN / 128), 256, 0, stream>>>(X, W, b, idx, out);
  }
}

// Round 5
// 389.940 us; speedup vs baseline: 1.7858x; 1.0320x over previous
//
#include <hip/hip_runtime.h>
#include <stdint.h>

// SageLayer: N=8192, F=1024, O=1024, K=2F=2048, NUM_NEIGH=10. Inputs f32.
#define NN 8192
#define FD 1024
#define OD 1024
#define KD 2048
#define NB 10

typedef short bf16x8 __attribute__((ext_vector_type(8)));
typedef float f32x4  __attribute__((ext_vector_type(4)));

static __device__ __forceinline__ float bf2f(ushort u) {
  union { uint32_t i; float f; } v; v.i = ((uint32_t)u) << 16; return v.f;
}
static __device__ __forceinline__ ushort f2bf(float f) {
  union { float f; uint32_t i; } v; v.f = f;
  uint32_t x = v.i;
  return (ushort)((x + 0x7FFFu + ((x >> 16) & 1u)) >> 16);  // RNE
}
static __device__ __forceinline__ bf16x8 cvt8(const float* p) {
  const float4 a = *reinterpret_cast<const float4*>(p);
  const float4 b = *reinterpret_cast<const float4*>(p + 4);
  bf16x8 v;
  v[0] = (short)f2bf(a.x); v[1] = (short)f2bf(a.y);
  v[2] = (short)f2bf(a.z); v[3] = (short)f2bf(a.w);
  v[4] = (short)f2bf(b.x); v[5] = (short)f2bf(b.y);
  v[6] = (short)f2bf(b.z); v[7] = (short)f2bf(b.w);
  return v;
}

// async global->LDS, 16 B/lane. LDS dest must be wave-uniform base + lane*16.
static __device__ __forceinline__ void async16(const ushort* g, ushort* l) {
  __builtin_amdgcn_global_load_lds(
      (const __attribute__((address_space(1))) uint32_t*)(const void*)g,
      (__attribute__((address_space(3))) uint32_t*)(void*)l, 16, 0, 0);
}

// ---------------------------------------------------------------------------
// xconv: Ab[i][0:1024] = bf16(X[i][:]).  Ab row stride = KD (2048).
// ---------------------------------------------------------------------------
__global__ __launch_bounds__(256) void xconv(const float* __restrict__ X,
                                             ushort* __restrict__ Ab) {
  const int q   = blockIdx.x * 256 + threadIdx.x;
  const int row = q >> 7;
  const int col = (q & 127) * 8;
  const bf16x8 v = cvt8(X + (size_t)row * FD + col);
  *reinterpret_cast<bf16x8*>(Ab + (size_t)row * KD + col) = v;
}

// ---------------------------------------------------------------------------
// aggk: Ab[i][1024:2048] = bf16(mean_j Xb[idx[i][j]][:]), gathering bf16 rows
// from Ab's left half. 2 rows per 256-thread block.
// ---------------------------------------------------------------------------
__global__ __launch_bounds__(256) void aggk(const int* __restrict__ idx,
                                            ushort* __restrict__ Ab) {
  const int row  = blockIdx.x * 2 + (threadIdx.x >> 7);
  const int lane = threadIdx.x & 127;
  const int col  = lane * 8;
  const int* ip = idx + (size_t)row * NB;
  int nb[NB];
#pragma unroll
  for (int j = 0; j < NB; ++j) nb[j] = ip[j];
  float acc[8] = {0.f, 0.f, 0.f, 0.f, 0.f, 0.f, 0.f, 0.f};
#pragma unroll
  for (int j = 0; j < NB; ++j) {
    const uint4 v = *reinterpret_cast<const uint4*>(Ab + (size_t)nb[j] * KD + col);
    const ushort* u = reinterpret_cast<const ushort*>(&v);
#pragma unroll
    for (int e = 0; e < 8; ++e) acc[e] += bf2f(u[e]);
  }
  bf16x8 o;
#pragma unroll
  for (int e = 0; e < 8; ++e) o[e] = (short)f2bf(acc[e] * 0.1f);
  *reinterpret_cast<bf16x8*>(Ab + (size_t)row * KD + FD + col) = o;
}

// ---------------------------------------------------------------------------
// wconv: Wtb[n][k] = bf16(W[k][n]).  64x64 LDS-tiled transpose + convert.
// ---------------------------------------------------------------------------
__global__ __launch_bounds__(1024) void wconv(const float* __restrict__ W,
                                              ushort* __restrict__ Wtb) {
  __shared__ float tile[64][65];
  const int k0 = blockIdx.x * 64;
  const int n0 = blockIdx.y * 64;
  const int tx = threadIdx.x;
  const int ty = threadIdx.y;
#pragma unroll
  for (int r = 0; r < 4; ++r) {
    const int kl = ty + r * 16;
    tile[kl][tx] = W[(size_t)(k0 + kl) * OD + n0 + tx];
  }
  __syncthreads();
#pragma unroll
  for (int r = 0; r < 4; ++r) {
    const int nl = ty + r * 16;
    Wtb[(size_t)(n0 + nl) * KD + k0 + tx] = f2bf(tile[tx][nl]);
  }
}

// ---------------------------------------------------------------------------
// gemm_fast3: Out = Ab @ Wtb^T + b.  128x128 tile, BK=64 (32 iters, half the
// barriers of r4), chunk-rotation LDS swizzle slot(r,c)=r*64+((c+r)&7)*8 so
// both staging (lane-contiguous, forced by global_load_lds) and ds_read_b128
// fragment reads stay at the 8-lane/4-bank optimum. XCD-aware 1-D grid
// swizzle: each XCD owns a contiguous m-range (A slice 4 MB -> L2-resident).
// ---------------------------------------------------------------------------
__global__ __launch_bounds__(256, 2) void gemm_fast3(const ushort* __restrict__ Ab,
                                                     const ushort* __restrict__ Wtb,
                                                     const float* __restrict__ Bias,
                                                     float* __restrict__ Out) {
  __shared__ ushort lA[128 * 64];  // 16 KB, swizzled [row][chunk]
  __shared__ ushort lB[128 * 64];  // 16 KB
  const int t  = threadIdx.x;
  // XCD-aware decode: id%8 ~ XCD; XCD c -> m-blocks [8c,8c+8), all 8 n-blocks
  const int id  = blockIdx.x;          // 0..511
  const int xcd = id & 7;
  const int j   = id >> 3;             // 0..63
  const int m0  = (xcd * 8 + (j >> 3)) * 128;
  const int n0  = (j & 7) * 128;

  const int wave = t >> 6;
  const int lane = t & 63;
  const int wm   = (wave & 1) * 64;
  const int wn   = (wave >> 1) * 64;
  const int l15  = lane & 15;
  const int quad = lane >> 4;

  f32x4 acc[4][4];
#pragma unroll
  for (int i = 0; i < 4; ++i)
#pragma unroll
    for (int jj = 0; jj < 4; ++jj) acc[i][jj] = (f32x4){0.f, 0.f, 0.f, 0.f};

  // staging coords: 4 slots per thread per matrix; slot q holds global chunk
  // c = (ch - row) & 7  (so that swizzled slot offset == lane-contiguous q*8)
  const ushort* gA[4];
  const ushort* gB[4];
#pragma unroll
  for (int i = 0; i < 4; ++i) {
    const int q   = i * 256 + t;       // 0..1023
    const int row = q >> 3;            // 0..127
    const int ch  = q & 7;
    const int c   = (ch - row) & 7;    // source k-chunk (8 elems)
    gA[i] = Ab  + (size_t)(m0 + row) * KD + c * 8;
    gB[i] = Wtb + (size_t)(n0 + row) * KD + c * 8;
  }

  for (int k0 = 0; k0 < KD; k0 += 64) {
#pragma unroll
    for (int i = 0; i < 4; ++i) {
      async16(gA[i] + k0, lA + (i * 256 + t) * 8);
      async16(gB[i] + k0, lB + (i * 256 + t) * 8);
    }
    __syncthreads();  // drains vmcnt -> staged data visible

#pragma unroll
    for (int s = 0; s < 2; ++s) {
      const int c = s * 4 + quad;  // k-chunk this lane needs
      bf16x8 afr[4], bfr[4];
#pragma unroll
      for (int mi = 0; mi < 4; ++mi) {
        const int r = wm + mi * 16 + l15;
        afr[mi] = *reinterpret_cast<const bf16x8*>(lA + r * 64 + ((c + r) & 7) * 8);
      }
#pragma unroll
      for (int ni = 0; ni < 4; ++ni) {
        const int r = wn + ni * 16 + l15;
        bfr[ni] = *reinterpret_cast<const bf16x8*>(lB + r * 64 + ((c + r) & 7) * 8);
      }
#pragma unroll
      for (int mi = 0; mi < 4; ++mi)
#pragma unroll
        for (int ni = 0; ni < 4; ++ni)
          acc[mi][ni] = __builtin_amdgcn_mfma_f32_16x16x32_bf16(afr[mi], bfr[ni], acc[mi][ni], 0, 0, 0);
    }
    __syncthreads();
  }

  // epilogue: C/D layout col=lane&15, row=quad*4+reg (verified r2-r4)
#pragma unroll
  for (int ni = 0; ni < 4; ++ni) {
    const int gn = n0 + wn + ni * 16 + l15;
    const float bv = Bias[gn];
#pragma unroll
    for (int mi = 0; mi < 4; ++mi) {
      const int gm = m0 + wm + mi * 16 + quad * 4;
#pragma unroll
      for (int r = 0; r < 4; ++r)
        Out[(size_t)(gm + r) * OD + gn] = acc[mi][ni][r] + bv;
    }
  }
}

// ---------------------------------------------------------------------------
// Fallback (ws too small): round-2 fused kernel, known-correct.
// ---------------------------------------------------------------------------
__global__ __launch_bounds__(256) void gemm_fused(const float* __restrict__ X,
                                                  const float* __restrict__ W,
                                                  const float* __restrict__ Bias,
                                                  const int* __restrict__ idx,
                                                  float* __restrict__ Out) {
  __shared__ ushort lA[128 * 32];
  __shared__ ushort lB[32 * 128];
  const int t    = threadIdx.x;
  const int m0   = blockIdx.y * 128;
  const int n0   = blockIdx.x * 128;
  const int wave = t >> 6;
  const int lane = t & 63;
  const int wm   = (wave & 1) * 64;
  const int wn   = (wave >> 1) * 64;
  const int l15  = lane & 15;
  const int quad = lane >> 4;

  f32x4 acc[4][4];
#pragma unroll
  for (int i = 0; i < 4; ++i)
#pragma unroll
    for (int j = 0; j < 4; ++j) acc[i][j] = (f32x4){0.f, 0.f, 0.f, 0.f};

  for (int kt = 0; kt < KD / 32; ++kt) {
    const int k0 = kt * 32;
    if (k0 < FD) {
#pragma unroll
      for (int r = 0; r < 2; ++r) {
        const int q = r * 256 + t;
        const int row = q >> 2, ch = q & 3;
        *reinterpret_cast<bf16x8*>(lA + q * 8) =
            cvt8(X + (size_t)(m0 + row) * FD + k0 + ch * 8);
      }
    } else {
      const int kc = k0 - FD;
#pragma unroll
      for (int r = 0; r < 2; ++r) {
        const int q = r * 256 + t;
        const int row = q >> 2, ch = q & 3;
        float a8[8] = {0.f, 0.f, 0.f, 0.f, 0.f, 0.f, 0.f, 0.f};
        const int* ip = idx + (size_t)(m0 + row) * NB;
#pragma unroll
        for (int j = 0; j < NB; ++j) {
          const float* p = X + (size_t)ip[j] * FD + kc + ch * 8;
          const float4 a = *(const float4*)p;
          const float4 b = *(const float4*)(p + 4);
          a8[0] += a.x; a8[1] += a.y; a8[2] += a.z; a8[3] += a.w;
          a8[4] += b.x; a8[5] += b.y; a8[6] += b.z; a8[7] += b.w;
        }
        bf16x8 v;
#pragma unroll
        for (int e = 0; e < 8; ++e) v[e] = (short)f2bf(a8[e] * 0.1f);
        *reinterpret_cast<bf16x8*>(lA + q * 8) = v;
      }
    }
#pragma unroll
    for (int r = 0; r < 2; ++r) {
      const int q = r * 256 + t;
      const int kr = q >> 4, ch = q & 15;
      *reinterpret_cast<bf16x8*>(lB + q * 8) =
          cvt8(W + (size_t)(k0 + kr) * OD + n0 + ch * 8);
    }
    __syncthreads();

    bf16x8 afr[4], bfr[4];
#pragma unroll
    for (int mi = 0; mi < 4; ++mi)
      afr[mi] = *reinterpret_cast<const bf16x8*>(lA + (wm + mi * 16 + l15) * 32 + quad * 8);
#pragma unroll
    for (int ni = 0; ni < 4; ++ni) {
      const int col = wn + ni * 16 + l15;
#pragma unroll
      for (int j = 0; j < 8; ++j)
        bfr[ni][j] = (short)lB[(quad * 8 + j) * 128 + col];
    }
#pragma unroll
    for (int mi = 0; mi < 4; ++mi)
#pragma unroll
      for (int ni = 0; ni < 4; ++ni)
        acc[mi][ni] = __builtin_amdgcn_mfma_f32_16x16x32_bf16(afr[mi], bfr[ni], acc[mi][ni], 0, 0, 0);
    __syncthreads();
  }
#pragma unroll
  for (int ni = 0; ni < 4; ++ni) {
    const int gn = n0 + wn + ni * 16 + l15;
    const float bv = Bias[gn];
#pragma unroll
    for (int mi = 0; mi < 4; ++mi) {
      const int gm = m0 + wm + mi * 16 + quad * 4;
#pragma unroll
      for (int r = 0; r < 4; ++r)
        Out[(size_t)(gm + r) * OD + gn] = acc[mi][ni][r] + bv;
    }
  }
}

extern "C" void kernel_launch(void* const* d_in, const int* in_sizes, int n_in,
                              void* d_out, int out_size, void* d_ws, size_t ws_size,
                              hipStream_t stream) {
  const float* X   = (const float*)d_in[0];
  // d_in[1] = A: dead code in the reference
  const float* W   = (const float*)d_in[2];
  const float* b   = (const float*)d_in[3];
  const int*   idx = (const int*)d_in[4];
  float* out = (float*)d_out;

  const size_t need = ((size_t)NN * KD + (size_t)OD * KD) * sizeof(ushort);  // 36 MB
  if (ws_size >= need) {
    ushort* Ab  = (ushort*)d_ws;                 // [8192][2048] bf16, 32 MB
    ushort* Wtb = Ab + (size_t)NN * KD;          // [1024][2048] bf16, 4 MB

    xconv<<<NN * FD / (256 * 8), 256, 0, stream>>>(X, Ab);
    wconv<<<dim3(KD / 64, OD / 64), dim3(64, 16), 0, stream>>>(W, Wtb);
    aggk<<<NN / 2, 256, 0, stream>>>(idx, Ab);
    gemm_fast3<<<512, 256, 0, stream>>>(Ab, Wtb, b, out);
  } else {
    gemm_fused<<<dim3(OD / 128, NN / 128), 256, 0, stream>>>(X, W, b, idx, out);
  }
}